// Round 11
// baseline (335.213 us; speedup 1.0000x reference)
//
#include <hip/hip_runtime.h>

// Exact-order float32 arithmetic: numpy/jax evaluate left-to-right with no
// FMA contraction. hipcc defaults to -ffp-contract=fast, which would change
// rounding -> possible spike-time shift -> large voltage absmax error.
#pragma clang fp contract(off)

// R24 = R18 verbatim sim (best measured: 256-260 us/dispatch, absmax 0.0)
// + fill_cycle MERGED into the same kernel (second launch deleted).
// Rationale: R18's bench dur (293) vs dispatch (257) shows a ~35 us
// launch/dispatch gap for the trivial fill kernel. Six step-loop
// restructures (R14,R16,R17,R19-R23) all lost to R18 -> the step loop is at
// its local floor; the launch gap is the remaining recoverable time.
// Mechanics: threads 9-255 no longer return. Wave 0 executes the sim with
// lanes 0-8 under exec mask (ballot bits 9+ are 0, exactly as before when
// those lanes had returned). Lane 0 publishes (det, t_det, P) to LDS; one
// __syncthreads (compiler drains vmcnt before s_barrier -> wave 0's global
// stores are visible block-wide); then all 256 threads copy the periodic
// continuation in-kernel (incremental k = i mod P: one divide per thread,
// no per-element modulo). Outputs bit-identical to R18+fill_cycle.
// Sim details (R18, validated lineage R2..R23 absmax 0.0):
//   9-lane speculation, single ballot, SALU resolve, sel_mask I-select,
//   local recompute tail, fmaf(0.25f,t7,v) exact fusion, rolling-40 +
//   Brent pow-2 cycle detection, batched float4 flush per 8 steps.
// Lane map (wave 0):
//   0   : LLBN (no speculation: I2 depends only on prev-step bits)
//   1,2 : EBN  speculating z2 = 0,1
//   3,4 : IFN  speculating z3 = 0,1
//   5,6 : TN   speculating z3 = 0,1   (known z5p folded into candidates)
//   7,8 : MN   speculating z5 = 0,1

__device__ __forceinline__ float sel_mask(float a, float b, unsigned long long m) {
    float r;
    // D = m.bit[lane] ? S1 : S0   (VOP3 v_cndmask with SGPR-pair condition)
    asm("v_cndmask_b32 %0, %1, %2, %3" : "=v"(r) : "v"(a), "v"(b), "s"(m));
    return r;
}

__global__ __launch_bounds__(256) void net_sim(const float* __restrict__ mat,
                                               const float* __restrict__ w,
                                               float* __restrict__ out,
                                               int* __restrict__ ws,
                                               int T) {
    __shared__ double red[256];
    __shared__ int sdet[3];
    const int tid = threadIdx.x;

    // ---- z_plus = sum(input_mat * w0), f32 products accumulated in f64 ----
    const float w0 = w[0];
    double s = 0.0;
    for (int i = tid; i < 127 * 127; i += 256) {
        float p = mat[i] * w0;   // elementwise product rounded to f32 (as ref)
        s += (double)p;
    }
    red[tid] = s;
    __syncthreads();
    #pragma unroll
    for (int off = 128; off > 0; off >>= 1) {
        if (tid < off) red[tid] += red[tid + off];
        __syncthreads();
    }

    if (tid < 9) {   // 9 lanes of wave 0 run the sim (lanes 9-63 exec-masked)
        const float z_plus = (float)red[0];

        const float w2 = w[2], w3 = w[3], w5 = w[5], w6 = w[6], w7 = w[7],
                    w8 = w[8], w9 = w[9], w10 = w[10], w11 = w[11];
        const float zp_w1 = z_plus * w[1];
        const float zp_w4 = z_plus * w[4];

        // Validated constant-I set (R2..R23, absmax 0.0). z*w is exactly
        // +0.0f or w; x + (+0.0f) == x for the values involved.
        const float I2_00 = w2 * (zp_w1 - 0.0f) + w3 * 0.0f;   // (z2p, z4p)
        const float I2_10 = w2 * (zp_w1 - 0.0f) + w3 * 1.0f;
        const float I2_01 = w2 * (zp_w1 - w7)   + w3 * 0.0f;
        const float I2_11 = w2 * (zp_w1 - w7)   + w3 * 1.0f;
        const float I3_0  = zp_w4 + 0.0f * w5;
        const float I3_1  = zp_w4 + 1.0f * w5;
        const float I4_0  = 0.0f * w6;
        const float I4_1  = 1.0f * w6;
        const float I5_00 = w9 * (0.0f * w8) + w10 * 0.0f;     // (z3, z5p)
        const float I5_10 = w9 * (1.0f * w8) + w10 * 0.0f;
        const float I5_01 = w9 * (0.0f * w8) + w10 * 1.0f;
        const float I5_11 = w9 * (1.0f * w8) + w10 * 1.0f;
        const float I6_0  = 0.0f * w11;
        const float I6_1  = 1.0f * w11;

        const int lane = tid;  // 0..8
        const int g = lane == 0 ? 0 : lane <= 2 ? 1 : lane <= 4 ? 2
                    : lane <= 6 ? 3 : 4;

        // per-lane params; ka = float(TAU*DT*a) computed in f64 like Python
        const float ka = lane == 0 ? (float)(0.25 * 0.1) : (float)(0.25 * 0.02);
        const float b  = lane == 0 ? -0.075f : (g == 3 ? 0.2f : 0.25f);
        const float c  = g <= 1 ? -55.0f : -65.0f;
        const float d  = g == 1 ? 0.05f : 6.0f;
        float v = g == 0 ? -60.0f : (g == 3 ? -70.0f : -64.0f);
        float u = g == 0 ? 4.5f   : (g == 3 ? -14.0f : -16.0f);

        // candidate-I vectors: variant0/variant1 per group, z5p=0(a)/1(b).
        const float C0a = g == 0 ? I2_00 : g == 1 ? I3_0 : g == 2 ? I4_0
                        : g == 3 ? I5_00 : I6_0;
        const float C0b = g == 0 ? I2_00 : g == 1 ? I3_0 : g == 2 ? I4_0
                        : g == 3 ? I5_01 : I6_0;
        const float C1a = g == 1 ? I3_1 : g == 2 ? I4_1 : g == 3 ? I5_10
                        : g == 4 ? I6_1 : 0.0f;
        const float C1b = g == 1 ? I3_1 : g == 2 ? I4_1 : g == 3 ? I5_11
                        : g == 4 ? I6_1 : 0.0f;

        const bool is_lane0  = (lane == 0);
        const bool spec_var1 = (lane == 2) | (lane == 4) | (lane == 6)
                             | (lane == 8);

        float* __restrict__ psp = out + g * T;           // spikes row
        float* __restrict__ pvv = out + 5 * T + g * T;   // volts row

        int z2 = 0, z4 = 0, z5 = 0;   // prev-step bits — uniform

        // ---- cycle-detection: rolling-40 anchor + Brent pow-2 fallback ----
        float rav = 0.0f, rau = 0.0f;
        int raz2 = 0, raz4 = 0, raz5 = 0, ra_t = -1;
        float cav = 0.0f, cau = 0.0f;
        int caz2 = 0, caz4 = 0, caz5 = 0, ca_t = -1;
        int next_coarse = 8;
        int t_det = -1, Pf = 0;
        int blk5 = 0;   // t/8 mod 5; 0 <=> t % 40 == 0

        float zb[8], vb[8];

        int t = 0;
        for (; t + 8 <= T; t += 8) {
            // ---- block top: anchor compares / refresh (R9 semantics) ----
            if (blk5 == 0) {
                if (ra_t >= 0) {
                    unsigned long long mv =
                        __ballot(__float_as_uint(v) == __float_as_uint(rav));
                    unsigned long long mu =
                        __ballot(__float_as_uint(u) == __float_as_uint(rau));
                    if (((mv & mu) & 0x1FFull) == 0x1FFull &&
                        z2 == raz2 && z4 == raz4 && z5 == raz5) {
                        t_det = t; Pf = t - ra_t;   // Pf == 40
                        break;
                    }
                }
                if (t) { rav = v; rau = u; raz2 = z2; raz4 = z4; raz5 = z5;
                         ra_t = t; }
            } else if (ca_t >= 0) {
                unsigned long long mv =
                    __ballot(__float_as_uint(v) == __float_as_uint(cav));
                unsigned long long mu =
                    __ballot(__float_as_uint(u) == __float_as_uint(cau));
                if (((mv & mu) & 0x1FFull) == 0x1FFull &&
                    z2 == caz2 && z4 == caz4 && z5 == caz5) {
                    t_det = t; Pf = t - ca_t;
                    break;
                }
            }
            if (t == next_coarse) {
                cav = v; cau = u; caz2 = z2; caz4 = z4; caz5 = z5; ca_t = t;
                next_coarse <<= 1;
            }
            blk5 = (blk5 == 4) ? 0 : (blk5 + 1);

            #pragma unroll
            for (int j = 0; j < 8; ++j) {
                // candidate-I prep from prev-step bits (off critical path)
                float fI2 = z4 ? (z2 ? I2_11 : I2_01) : (z2 ? I2_10 : I2_00);
                float V0 = z5 ? C0b : C0a;
                float V1 = z5 ? C1b : C1a;
                V0 = is_lane0 ? fI2 : V0;
                float Ib = spec_var1 ? V1 : V0;

                // common izh head (I-independent)
                float t1 = 0.04f * v;
                float t2 = t1 * v;
                float t3 = 5.0f * v;
                float t4 = t2 + t3;
                float t5 = t4 + 140.0f;
                float t6 = t5 - u;
                float bv = b * v;
                float bvu = bv - u;
                float du = ka * bvu;
                float u1 = u + du;

                // speculative (ballot) tail — fmaf exact (R18-validated)
                float t7b = t6 + Ib;
                float v1b = fmaf(0.25f, t7b, v);   // TAU*DT = 0.25 exactly
                unsigned long long m = __ballot(v1b >= 30.0f);

                // scalar resolution (uniform)
                int nz2 = (int)(m & 1ull);
                int z3  = (int)((m >> (1 + nz2)) & 1ull);
                int nz4 = (int)((m >> (3 + z3)) & 1ull);
                int nz5 = (int)((m >> (5 + z3)) & 1ull);
                unsigned long long ssel =
                    (nz2 ? 0x006ull : 0ull) | (z3 ? 0x078ull : 0ull)
                  | (nz5 ? 0x180ull : 0ull);

                // actual tail, recomputed locally; I via SGPR-pair mask
                float Ia = sel_mask(V0, V1, ssel);
                float t7a = t6 + Ia;
                float v1a = fmaf(0.25f, t7a, v);
                bool fa = (v1a >= 30.0f);
                v = fa ? c : v1a;
                float u1d = u1 + d;
                u = fa ? u1d : u1;           // z*d is exactly d or +0.0f

                zb[j] = fa ? 1.0f : 0.0f;
                vb[j] = v;

                z2 = nz2; z4 = nz4; z5 = nz5;
            }
            // batched flush (rows 16B-aligned at t; t % 8 == 0)
            *(float4*)(psp)     = make_float4(zb[0], zb[1], zb[2], zb[3]);
            *(float4*)(psp + 4) = make_float4(zb[4], zb[5], zb[6], zb[7]);
            *(float4*)(pvv)     = make_float4(vb[0], vb[1], vb[2], vb[3]);
            *(float4*)(pvv + 4) = make_float4(vb[4], vb[5], vb[6], vb[7]);
            psp += 8;
            pvv += 8;
        }
        // tail (T not divisible by 8), only when no cycle was detected
        for (; t < T && t_det < 0; ++t) {
            float fI2 = z4 ? (z2 ? I2_11 : I2_01) : (z2 ? I2_10 : I2_00);
            float V0 = z5 ? C0b : C0a;
            float V1 = z5 ? C1b : C1a;
            V0 = is_lane0 ? fI2 : V0;
            float Ib = spec_var1 ? V1 : V0;
            float t1 = 0.04f * v;
            float t2 = t1 * v;
            float t3 = 5.0f * v;
            float t4 = t2 + t3;
            float t5 = t4 + 140.0f;
            float t6 = t5 - u;
            float bv = b * v;
            float bvu = bv - u;
            float du = ka * bvu;
            float u1 = u + du;
            float t7b = t6 + Ib;
            float v1b = fmaf(0.25f, t7b, v);
            unsigned long long m = __ballot(v1b >= 30.0f);
            int nz2 = (int)(m & 1ull);
            int z3  = (int)((m >> (1 + nz2)) & 1ull);
            int nz4 = (int)((m >> (3 + z3)) & 1ull);
            int nz5 = (int)((m >> (5 + z3)) & 1ull);
            unsigned long long ssel =
                (nz2 ? 0x006ull : 0ull) | (z3 ? 0x078ull : 0ull)
              | (nz5 ? 0x180ull : 0ull);
            float Ia = sel_mask(V0, V1, ssel);
            float t7a = t6 + Ia;
            float v1a = fmaf(0.25f, t7a, v);
            bool fa = (v1a >= 30.0f);
            v = fa ? c : v1a;
            float u1d = u1 + d;
            u = fa ? u1d : u1;
            psp[0] = fa ? 1.0f : 0.0f;
            pvv[0] = v;
            ++psp; ++pvv;
            z2 = nz2; z4 = nz4; z5 = nz5;
        }

        // publish detection result (ws re-poisoned before every call) +
        // block-wide broadcast via LDS
        if (lane == 0) {
            ws[0] = (t_det >= 0) ? 1 : 0;
            ws[1] = t_det;
            ws[2] = Pf;
            sdet[0] = (t_det >= 0) ? 1 : 0;
            sdet[1] = t_det;
            sdet[2] = Pf;
        }
    }

    // ---- in-kernel periodic fill (replaces the fill_cycle launch) ----
    __syncthreads();   // drains wave 0's stores; sdet visible to all
    if (sdet[0]) {
        const int t0 = sdet[1];
        const int P  = sdet[2];
        const int n  = T - t0;
        if (n > 0) {
            const int stp = 256 % P;         // uniform
            int k0 = tid % P;                // one divide per thread
            for (int r = 0; r < 10; ++r) {
                const float* __restrict__ src = out + (size_t)r * T + (t0 - P);
                float* __restrict__ dst       = out + (size_t)r * T + t0;
                int k = k0;
                for (int i = tid; i < n; i += 256) {
                    dst[i] = src[k];
                    k += stp; if (k >= P) k -= P;
                }
            }
        }
    }
}

extern "C" void kernel_launch(void* const* d_in, const int* in_sizes, int n_in,
                              void* d_out, int out_size, void* d_ws, size_t ws_size,
                              hipStream_t stream) {
    const float* mat = (const float*)d_in[0];
    const float* w   = (const float*)d_in[1];
    // out_size = 2 outputs * 5 neurons * T  -> T = out_size/10
    int T = out_size / 10;
    net_sim<<<1, 256, 0, stream>>>(mat, w, (float*)d_out, (int*)d_ws, T);
}

// Round 12
// 301.341 us; speedup vs baseline: 1.1124x; 1.1124x over previous
//
#include <hip/hip_runtime.h>

// Exact-order float32 arithmetic: numpy/jax evaluate left-to-right with no
// FMA contraction. hipcc defaults to -ffp-contract=fast, which would change
// rounding -> possible spike-time shift -> large voltage absmax error.
#pragma clang fp contract(off)

// R25 = R18 (champion: 256-260 us/dispatch, absmax 0.0) + ONE minimal
// chain cut, everything else verbatim (incl. separate fill_cycle launch;
// R24's merged fill was slower).
// The cut: R18's post-resolve chain was
//   ssel -> cndmask(Ia) -> v_add(t7a) -> v_fma(v1a) -> v_cmp -> cndmask x2.
// R25 computes the COMPLEMENT-variant candidate pre-ballot (pure ILP):
//   Io = spec_var1 ? V0 : V1;  v1o = fmaf(0.25f, t6+Io, v)
// and post-resolve selects instead of recomputing:
//   v1a = sel_mask(v1b, v1o, ssel ^ 0x154)
// One cndmask replaces cndmask+add+fma (-2 dependent VALU, +1 off-path
// SALU xor, +2 issue slots). Correctness of the xor mask: a lane must take
// the complement iff its hypothesis bit != resolved variant bit; ssel holds
// the resolved bits replicated per pair {1,2}{3,4}{5,6}{7,8}, 0x154 is the
// hypothesis-=1 lane set {2,4,6,8}; lane 0 is 0 in both (LLBN always keeps
// its true-I2 candidate). The selected v1a is produced by the identical
// f32 op sequence as R18's recompute -> bitwise identical outputs
// (absmax 0.0 lineage R2..R24). fa/v/u/zb follow R18 verbatim.
// Lane map (wave 0):
//   0   : LLBN (no speculation: I2 depends only on prev-step bits)
//   1,2 : EBN  speculating z2 = 0,1
//   3,4 : IFN  speculating z3 = 0,1
//   5,6 : TN   speculating z3 = 0,1   (known z5p folded into candidates)
//   7,8 : MN   speculating z5 = 0,1
// Cycle detection: rolling-40 anchor (t%40==0 block tops) + Brent pow-2
// fallback; state = {v,u} x 9 lanes + carry bits. fill_cycle copies the
// periodic continuation.

__device__ __forceinline__ float sel_mask(float a, float b, unsigned long long m) {
    float r;
    // D = m.bit[lane] ? S1 : S0   (VOP3 v_cndmask with SGPR-pair condition)
    asm("v_cndmask_b32 %0, %1, %2, %3" : "=v"(r) : "v"(a), "v"(b), "s"(m));
    return r;
}

__global__ __launch_bounds__(256) void net_sim(const float* __restrict__ mat,
                                               const float* __restrict__ w,
                                               float* __restrict__ out,
                                               int* __restrict__ ws,
                                               int T) {
    __shared__ double red[256];
    const int tid = threadIdx.x;

    // ---- z_plus = sum(input_mat * w0), f32 products accumulated in f64 ----
    const float w0 = w[0];
    double s = 0.0;
    for (int i = tid; i < 127 * 127; i += 256) {
        float p = mat[i] * w0;   // elementwise product rounded to f32 (as ref)
        s += (double)p;
    }
    red[tid] = s;
    __syncthreads();
    #pragma unroll
    for (int off = 128; off > 0; off >>= 1) {
        if (tid < off) red[tid] += red[tid + off];
        __syncthreads();
    }
    if (tid >= 9) return;   // 9 lanes of wave 0 continue; no more barriers

    const float z_plus = (float)red[0];

    const float w2 = w[2], w3 = w[3], w5 = w[5], w6 = w[6], w7 = w[7],
                w8 = w[8], w9 = w[9], w10 = w[10], w11 = w[11];
    const float zp_w1 = z_plus * w[1];
    const float zp_w4 = z_plus * w[4];

    // Validated constant-I set (R2..R24, absmax 0.0). z*w is exactly +0.0f
    // or w; x + (+0.0f) == x for the values involved.
    const float I2_00 = w2 * (zp_w1 - 0.0f) + w3 * 0.0f;   // (z2p, z4p)
    const float I2_10 = w2 * (zp_w1 - 0.0f) + w3 * 1.0f;
    const float I2_01 = w2 * (zp_w1 - w7)   + w3 * 0.0f;
    const float I2_11 = w2 * (zp_w1 - w7)   + w3 * 1.0f;
    const float I3_0  = zp_w4 + 0.0f * w5;
    const float I3_1  = zp_w4 + 1.0f * w5;
    const float I4_0  = 0.0f * w6;
    const float I4_1  = 1.0f * w6;
    const float I5_00 = w9 * (0.0f * w8) + w10 * 0.0f;     // (z3, z5p)
    const float I5_10 = w9 * (1.0f * w8) + w10 * 0.0f;
    const float I5_01 = w9 * (0.0f * w8) + w10 * 1.0f;
    const float I5_11 = w9 * (1.0f * w8) + w10 * 1.0f;
    const float I6_0  = 0.0f * w11;
    const float I6_1  = 1.0f * w11;

    const int lane = tid;  // 0..8
    const int g = lane == 0 ? 0 : lane <= 2 ? 1 : lane <= 4 ? 2 : lane <= 6 ? 3 : 4;

    // per-lane params; ka = float(TAU*DT*a) computed in f64 like Python
    const float ka = lane == 0 ? (float)(0.25 * 0.1) : (float)(0.25 * 0.02);
    const float b  = lane == 0 ? -0.075f : (g == 3 ? 0.2f : 0.25f);
    const float c  = g <= 1 ? -55.0f : -65.0f;
    const float d  = g == 1 ? 0.05f : 6.0f;
    float v = g == 0 ? -60.0f : (g == 3 ? -70.0f : -64.0f);
    float u = g == 0 ? 4.5f   : (g == 3 ? -14.0f : -16.0f);

    // candidate-I vectors: variant0/variant1 per group, for z5p=0(a)/1(b).
    const float C0a = g == 0 ? I2_00 : g == 1 ? I3_0 : g == 2 ? I4_0
                    : g == 3 ? I5_00 : I6_0;
    const float C0b = g == 0 ? I2_00 : g == 1 ? I3_0 : g == 2 ? I4_0
                    : g == 3 ? I5_01 : I6_0;
    const float C1a = g == 1 ? I3_1 : g == 2 ? I4_1 : g == 3 ? I5_10
                    : g == 4 ? I6_1 : 0.0f;
    const float C1b = g == 1 ? I3_1 : g == 2 ? I4_1 : g == 3 ? I5_11
                    : g == 4 ? I6_1 : 0.0f;

    const bool is_lane0  = (lane == 0);
    const bool spec_var1 = (lane == 2) | (lane == 4) | (lane == 6) | (lane == 8);

    float* __restrict__ psp = out + g * T;           // spikes row
    float* __restrict__ pvv = out + 5 * T + g * T;   // volts row

    int z2 = 0, z4 = 0, z5 = 0;   // prev-step bits (z2p, z4p, z5p) — uniform

    // ---- cycle-detection: rolling-40 anchor + Brent pow-2 fallback ----
    float rav = 0.0f, rau = 0.0f; int raz2 = 0, raz4 = 0, raz5 = 0, ra_t = -1;
    float cav = 0.0f, cau = 0.0f; int caz2 = 0, caz4 = 0, caz5 = 0, ca_t = -1;
    int next_coarse = 8;
    int t_det = -1, Pf = 0;
    int blk5 = 0;   // t/8 mod 5; 0 <=> t % 40 == 0

    float zb[8], vb[8];

    int t = 0;
    for (; t + 8 <= T; t += 8) {
        // ---- block top: anchor compares / refresh (R9 semantics) ----
        if (blk5 == 0) {
            if (ra_t >= 0) {
                unsigned long long mv =
                    __ballot(__float_as_uint(v) == __float_as_uint(rav));
                unsigned long long mu =
                    __ballot(__float_as_uint(u) == __float_as_uint(rau));
                if (((mv & mu) & 0x1FFull) == 0x1FFull &&
                    z2 == raz2 && z4 == raz4 && z5 == raz5) {
                    t_det = t; Pf = t - ra_t;   // Pf == 40
                    break;
                }
            }
            if (t) { rav = v; rau = u; raz2 = z2; raz4 = z4; raz5 = z5; ra_t = t; }
        } else if (ca_t >= 0) {
            unsigned long long mv =
                __ballot(__float_as_uint(v) == __float_as_uint(cav));
            unsigned long long mu =
                __ballot(__float_as_uint(u) == __float_as_uint(cau));
            if (((mv & mu) & 0x1FFull) == 0x1FFull &&
                z2 == caz2 && z4 == caz4 && z5 == caz5) {
                t_det = t; Pf = t - ca_t;
                break;
            }
        }
        if (t == next_coarse) {
            cav = v; cau = u; caz2 = z2; caz4 = z4; caz5 = z5; ca_t = t;
            next_coarse <<= 1;
        }
        blk5 = (blk5 == 4) ? 0 : (blk5 + 1);

        #pragma unroll
        for (int j = 0; j < 8; ++j) {
            // candidate-I prep from prev-step bits (off critical path)
            float fI2 = z4 ? (z2 ? I2_11 : I2_01) : (z2 ? I2_10 : I2_00);
            float V0 = z5 ? C0b : C0a;
            float V1 = z5 ? C1b : C1a;
            V0 = is_lane0 ? fI2 : V0;
            float Ib = spec_var1 ? V1 : V0;
            float Io = spec_var1 ? V0 : V1;   // complement variant

            // common izh head (I-independent)
            float t1 = 0.04f * v;
            float t2 = t1 * v;
            float t3 = 5.0f * v;
            float t4 = t2 + t3;
            float t5 = t4 + 140.0f;
            float t6 = t5 - u;
            float bv = b * v;
            float bvu = bv - u;
            float du = ka * bvu;
            float u1 = u + du;

            // speculative tail + complement tail (parallel ILP); fmaf exact
            float t7b = t6 + Ib;
            float v1b = fmaf(0.25f, t7b, v);   // TAU*DT = 0.25 exactly
            float t7o = t6 + Io;
            float v1o = fmaf(0.25f, t7o, v);
            unsigned long long m = __ballot(v1b >= 30.0f);

            // scalar resolution (uniform) — R18 verbatim
            int nz2 = (int)(m & 1ull);
            int z3  = (int)((m >> (1 + nz2)) & 1ull);
            int nz4 = (int)((m >> (3 + z3)) & 1ull);
            int nz5 = (int)((m >> (5 + z3)) & 1ull);
            unsigned long long ssel =
                (nz2 ? 0x006ull : 0ull) | (z3 ? 0x078ull : 0ull)
              | (nz5 ? 0x180ull : 0ull);
            unsigned long long sot = ssel ^ 0x154ull;  // take-complement mask

            // actual value = select, not recompute (bitwise == R18's v1a)
            float v1a = sel_mask(v1b, v1o, sot);
            bool fa = (v1a >= 30.0f);
            v = fa ? c : v1a;
            float u1d = u1 + d;
            u = fa ? u1d : u1;           // z*d is exactly d or +0.0f

            zb[j] = fa ? 1.0f : 0.0f;
            vb[j] = v;

            z2 = nz2; z4 = nz4; z5 = nz5;
        }
        // batched flush (rows 16B-aligned at t; t % 8 == 0)
        *(float4*)(psp)     = make_float4(zb[0], zb[1], zb[2], zb[3]);
        *(float4*)(psp + 4) = make_float4(zb[4], zb[5], zb[6], zb[7]);
        *(float4*)(pvv)     = make_float4(vb[0], vb[1], vb[2], vb[3]);
        *(float4*)(pvv + 4) = make_float4(vb[4], vb[5], vb[6], vb[7]);
        psp += 8;
        pvv += 8;
    }
    // tail (T not divisible by 8), only when no cycle was detected
    for (; t < T && t_det < 0; ++t) {
        float fI2 = z4 ? (z2 ? I2_11 : I2_01) : (z2 ? I2_10 : I2_00);
        float V0 = z5 ? C0b : C0a;
        float V1 = z5 ? C1b : C1a;
        V0 = is_lane0 ? fI2 : V0;
        float Ib = spec_var1 ? V1 : V0;
        float Io = spec_var1 ? V0 : V1;
        float t1 = 0.04f * v;
        float t2 = t1 * v;
        float t3 = 5.0f * v;
        float t4 = t2 + t3;
        float t5 = t4 + 140.0f;
        float t6 = t5 - u;
        float bv = b * v;
        float bvu = bv - u;
        float du = ka * bvu;
        float u1 = u + du;
        float t7b = t6 + Ib;
        float v1b = fmaf(0.25f, t7b, v);
        float t7o = t6 + Io;
        float v1o = fmaf(0.25f, t7o, v);
        unsigned long long m = __ballot(v1b >= 30.0f);
        int nz2 = (int)(m & 1ull);
        int z3  = (int)((m >> (1 + nz2)) & 1ull);
        int nz4 = (int)((m >> (3 + z3)) & 1ull);
        int nz5 = (int)((m >> (5 + z3)) & 1ull);
        unsigned long long ssel =
            (nz2 ? 0x006ull : 0ull) | (z3 ? 0x078ull : 0ull)
          | (nz5 ? 0x180ull : 0ull);
        unsigned long long sot = ssel ^ 0x154ull;
        float v1a = sel_mask(v1b, v1o, sot);
        bool fa = (v1a >= 30.0f);
        v = fa ? c : v1a;
        float u1d = u1 + d;
        u = fa ? u1d : u1;
        psp[0] = fa ? 1.0f : 0.0f;
        pvv[0] = v;
        ++psp; ++pvv;
        z2 = nz2; z4 = nz4; z5 = nz5;
    }

    // publish detection result (ws is re-poisoned before every call)
    if (lane == 0) {
        ws[0] = (t_det >= 0) ? 1 : 0;
        ws[1] = t_det;
        ws[2] = Pf;
    }
}

// Fills out[r, t] for t in [t_det, T) with the periodic continuation
// out[r, t_det - P + ((t - t_det) mod P)]. No-op when no cycle was found.
__global__ __launch_bounds__(256) void fill_cycle(float* __restrict__ out,
                                                  const int* __restrict__ ws,
                                                  int T) {
    if (ws[0] == 0) return;
    const int t0 = ws[1];
    const int P  = ws[2];
    const int r  = blockIdx.y;                    // 0..9 (row)
    const float* __restrict__ src = out + (size_t)r * T + (t0 - P);
    float* __restrict__ dst       = out + (size_t)r * T + t0;
    const int n = T - t0;
    for (int i = blockIdx.x * blockDim.x + threadIdx.x; i < n;
         i += gridDim.x * blockDim.x) {
        dst[i] = src[i % P];
    }
}

extern "C" void kernel_launch(void* const* d_in, const int* in_sizes, int n_in,
                              void* d_out, int out_size, void* d_ws, size_t ws_size,
                              hipStream_t stream) {
    const float* mat = (const float*)d_in[0];
    const float* w   = (const float*)d_in[1];
    // out_size = 2 outputs * 5 neurons * T  -> T = out_size/10
    int T = out_size / 10;
    net_sim<<<1, 256, 0, stream>>>(mat, w, (float*)d_out, (int*)d_ws, T);
    dim3 grid(40, 10, 1);
    fill_cycle<<<grid, 256, 0, stream>>>((float*)d_out, (const int*)d_ws, T);
}

// Round 13
// 293.352 us; speedup vs baseline: 1.1427x; 1.0272x over previous
//
#include <hip/hip_runtime.h>

// Exact-order float32 arithmetic: numpy/jax evaluate left-to-right with no
// FMA contraction. hipcc defaults to -ffp-contract=fast, which would change
// rounding -> possible spike-time shift -> large voltage absmax error.
#pragma clang fp contract(off)

// R26 = R18 VERBATIM (final revert; champion: 256-260 us/dispatch,
// absmax 0.0). Session ledger: R18's fmaf exact-fusion was the only win
// (274 -> 257). Eight step-loop restructures (R14 select-via-writelane,
// R16 DPP-partner-select, R17/R21 two-step speculation, R19 dual-ballot,
// R20 VALU-resolve [race], R22 one-lane, R23 pairs+select, R25 complement-
// select) ALL regressed -- including two that strictly removed dependent
// ops. R24 (merged fill) also regressed. Conclusion: this latency-bound
// serial recurrence is at its empirical floor with R18's exact instruction
// mix; every perturbation loses more to scheduling second-order effects
// than it gains.
// Structure: 9-lane speculation on wave 0; single ballot/step; uniform SALU
// resolve; SGPR-pair-mask cndmask I-select; local recompute tail with
// fmaf(0.25f,t7,v) (bitwise == v+(0.25f*t7): 0.25*x is a pure exponent
// shift); rolling-40 anchor (t%40==0 block tops) + Brent pow-2 fallback
// cycle detection on bitwise state; batched float4 flush per 8 steps;
// separate fill_cycle kernel copies the periodic continuation.
// Lane map (wave 0):
//   0   : LLBN (no speculation: I2 depends only on prev-step bits)
//   1,2 : EBN  speculating z2 = 0,1
//   3,4 : IFN  speculating z3 = 0,1
//   5,6 : TN   speculating z3 = 0,1   (known z5p folded into candidates)
//   7,8 : MN   speculating z5 = 0,1

__device__ __forceinline__ float sel_mask(float a, float b, unsigned long long m) {
    float r;
    // D = m.bit[lane] ? S1 : S0   (VOP3 v_cndmask with SGPR-pair condition)
    asm("v_cndmask_b32 %0, %1, %2, %3" : "=v"(r) : "v"(a), "v"(b), "s"(m));
    return r;
}

__global__ __launch_bounds__(256) void net_sim(const float* __restrict__ mat,
                                               const float* __restrict__ w,
                                               float* __restrict__ out,
                                               int* __restrict__ ws,
                                               int T) {
    __shared__ double red[256];
    const int tid = threadIdx.x;

    // ---- z_plus = sum(input_mat * w0), f32 products accumulated in f64 ----
    const float w0 = w[0];
    double s = 0.0;
    for (int i = tid; i < 127 * 127; i += 256) {
        float p = mat[i] * w0;   // elementwise product rounded to f32 (as ref)
        s += (double)p;
    }
    red[tid] = s;
    __syncthreads();
    #pragma unroll
    for (int off = 128; off > 0; off >>= 1) {
        if (tid < off) red[tid] += red[tid + off];
        __syncthreads();
    }
    if (tid >= 9) return;   // 9 lanes of wave 0 continue; no more barriers

    const float z_plus = (float)red[0];

    const float w2 = w[2], w3 = w[3], w5 = w[5], w6 = w[6], w7 = w[7],
                w8 = w[8], w9 = w[9], w10 = w[10], w11 = w[11];
    const float zp_w1 = z_plus * w[1];
    const float zp_w4 = z_plus * w[4];

    // Validated constant-I set (R2..R25, absmax 0.0). z*w is exactly +0.0f
    // or w; x + (+0.0f) == x for the values involved.
    const float I2_00 = w2 * (zp_w1 - 0.0f) + w3 * 0.0f;   // (z2p, z4p)
    const float I2_10 = w2 * (zp_w1 - 0.0f) + w3 * 1.0f;
    const float I2_01 = w2 * (zp_w1 - w7)   + w3 * 0.0f;
    const float I2_11 = w2 * (zp_w1 - w7)   + w3 * 1.0f;
    const float I3_0  = zp_w4 + 0.0f * w5;
    const float I3_1  = zp_w4 + 1.0f * w5;
    const float I4_0  = 0.0f * w6;
    const float I4_1  = 1.0f * w6;
    const float I5_00 = w9 * (0.0f * w8) + w10 * 0.0f;     // (z3, z5p)
    const float I5_10 = w9 * (1.0f * w8) + w10 * 0.0f;
    const float I5_01 = w9 * (0.0f * w8) + w10 * 1.0f;
    const float I5_11 = w9 * (1.0f * w8) + w10 * 1.0f;
    const float I6_0  = 0.0f * w11;
    const float I6_1  = 1.0f * w11;

    const int lane = tid;  // 0..8
    const int g = lane == 0 ? 0 : lane <= 2 ? 1 : lane <= 4 ? 2 : lane <= 6 ? 3 : 4;

    // per-lane params; ka = float(TAU*DT*a) computed in f64 like Python
    const float ka = lane == 0 ? (float)(0.25 * 0.1) : (float)(0.25 * 0.02);
    const float b  = lane == 0 ? -0.075f : (g == 3 ? 0.2f : 0.25f);
    const float c  = g <= 1 ? -55.0f : -65.0f;
    const float d  = g == 1 ? 0.05f : 6.0f;
    float v = g == 0 ? -60.0f : (g == 3 ? -70.0f : -64.0f);
    float u = g == 0 ? 4.5f   : (g == 3 ? -14.0f : -16.0f);

    // candidate-I vectors: variant0/variant1 per group, for z5p=0(a)/1(b).
    const float C0a = g == 0 ? I2_00 : g == 1 ? I3_0 : g == 2 ? I4_0
                    : g == 3 ? I5_00 : I6_0;
    const float C0b = g == 0 ? I2_00 : g == 1 ? I3_0 : g == 2 ? I4_0
                    : g == 3 ? I5_01 : I6_0;
    const float C1a = g == 1 ? I3_1 : g == 2 ? I4_1 : g == 3 ? I5_10
                    : g == 4 ? I6_1 : 0.0f;
    const float C1b = g == 1 ? I3_1 : g == 2 ? I4_1 : g == 3 ? I5_11
                    : g == 4 ? I6_1 : 0.0f;

    const bool is_lane0  = (lane == 0);
    const bool spec_var1 = (lane == 2) | (lane == 4) | (lane == 6) | (lane == 8);

    float* __restrict__ psp = out + g * T;           // spikes row
    float* __restrict__ pvv = out + 5 * T + g * T;   // volts row

    int z2 = 0, z4 = 0, z5 = 0;   // prev-step bits (z2p, z4p, z5p) — uniform

    // ---- cycle-detection: rolling-40 anchor + Brent pow-2 fallback ----
    float rav = 0.0f, rau = 0.0f; int raz2 = 0, raz4 = 0, raz5 = 0, ra_t = -1;
    float cav = 0.0f, cau = 0.0f; int caz2 = 0, caz4 = 0, caz5 = 0, ca_t = -1;
    int next_coarse = 8;
    int t_det = -1, Pf = 0;
    int blk5 = 0;   // t/8 mod 5; 0 <=> t % 40 == 0

    float zb[8], vb[8];

    int t = 0;
    for (; t + 8 <= T; t += 8) {
        // ---- block top: anchor compares / refresh (R9 semantics) ----
        if (blk5 == 0) {
            if (ra_t >= 0) {
                unsigned long long mv =
                    __ballot(__float_as_uint(v) == __float_as_uint(rav));
                unsigned long long mu =
                    __ballot(__float_as_uint(u) == __float_as_uint(rau));
                if (((mv & mu) & 0x1FFull) == 0x1FFull &&
                    z2 == raz2 && z4 == raz4 && z5 == raz5) {
                    t_det = t; Pf = t - ra_t;   // Pf == 40
                    break;
                }
            }
            if (t) { rav = v; rau = u; raz2 = z2; raz4 = z4; raz5 = z5; ra_t = t; }
        } else if (ca_t >= 0) {
            unsigned long long mv =
                __ballot(__float_as_uint(v) == __float_as_uint(cav));
            unsigned long long mu =
                __ballot(__float_as_uint(u) == __float_as_uint(cau));
            if (((mv & mu) & 0x1FFull) == 0x1FFull &&
                z2 == caz2 && z4 == caz4 && z5 == caz5) {
                t_det = t; Pf = t - ca_t;
                break;
            }
        }
        if (t == next_coarse) {
            cav = v; cau = u; caz2 = z2; caz4 = z4; caz5 = z5; ca_t = t;
            next_coarse <<= 1;
        }
        blk5 = (blk5 == 4) ? 0 : (blk5 + 1);

        #pragma unroll
        for (int j = 0; j < 8; ++j) {
            // candidate-I prep from prev-step bits (off critical path)
            float fI2 = z4 ? (z2 ? I2_11 : I2_01) : (z2 ? I2_10 : I2_00);
            float V0 = z5 ? C0b : C0a;
            float V1 = z5 ? C1b : C1a;
            V0 = is_lane0 ? fI2 : V0;
            float Ib = spec_var1 ? V1 : V0;

            // common izh head (I-independent)
            float t1 = 0.04f * v;
            float t2 = t1 * v;
            float t3 = 5.0f * v;
            float t4 = t2 + t3;
            float t5 = t4 + 140.0f;
            float t6 = t5 - u;
            float bv = b * v;
            float bvu = bv - u;
            float du = ka * bvu;
            float u1 = u + du;

            // speculative (ballot) tail — fmaf(0.25,x,v) == v + (0.25f*x)
            // bitwise (0.25*x exact: pure exponent shift, no subnormals)
            float t7b = t6 + Ib;
            float v1b = fmaf(0.25f, t7b, v);   // TAU*DT = 0.25 exactly
            unsigned long long m = __ballot(v1b >= 30.0f);

            // scalar resolution (uniform)
            int nz2 = (int)(m & 1ull);
            int z3  = (int)((m >> (1 + nz2)) & 1ull);
            int nz4 = (int)((m >> (3 + z3)) & 1ull);
            int nz5 = (int)((m >> (5 + z3)) & 1ull);
            unsigned long long ssel =
                (nz2 ? 0x006ull : 0ull) | (z3 ? 0x078ull : 0ull)
              | (nz5 ? 0x180ull : 0ull);

            // actual tail, recomputed locally; I select via SGPR-pair mask
            float Ia = sel_mask(V0, V1, ssel);
            float t7a = t6 + Ia;
            float v1a = fmaf(0.25f, t7a, v);
            bool fa = (v1a >= 30.0f);
            v = fa ? c : v1a;
            float u1d = u1 + d;
            u = fa ? u1d : u1;           // z*d is exactly d or +0.0f

            zb[j] = fa ? 1.0f : 0.0f;
            vb[j] = v;

            z2 = nz2; z4 = nz4; z5 = nz5;
        }
        // batched flush (rows 16B-aligned at t; t % 8 == 0)
        *(float4*)(psp)     = make_float4(zb[0], zb[1], zb[2], zb[3]);
        *(float4*)(psp + 4) = make_float4(zb[4], zb[5], zb[6], zb[7]);
        *(float4*)(pvv)     = make_float4(vb[0], vb[1], vb[2], vb[3]);
        *(float4*)(pvv + 4) = make_float4(vb[4], vb[5], vb[6], vb[7]);
        psp += 8;
        pvv += 8;
    }
    // tail (T not divisible by 8), only when no cycle was detected
    for (; t < T && t_det < 0; ++t) {
        float fI2 = z4 ? (z2 ? I2_11 : I2_01) : (z2 ? I2_10 : I2_00);
        float V0 = z5 ? C0b : C0a;
        float V1 = z5 ? C1b : C1a;
        V0 = is_lane0 ? fI2 : V0;
        float Ib = spec_var1 ? V1 : V0;
        float t1 = 0.04f * v;
        float t2 = t1 * v;
        float t3 = 5.0f * v;
        float t4 = t2 + t3;
        float t5 = t4 + 140.0f;
        float t6 = t5 - u;
        float bv = b * v;
        float bvu = bv - u;
        float du = ka * bvu;
        float u1 = u + du;
        float t7b = t6 + Ib;
        float v1b = fmaf(0.25f, t7b, v);
        unsigned long long m = __ballot(v1b >= 30.0f);
        int nz2 = (int)(m & 1ull);
        int z3  = (int)((m >> (1 + nz2)) & 1ull);
        int nz4 = (int)((m >> (3 + z3)) & 1ull);
        int nz5 = (int)((m >> (5 + z3)) & 1ull);
        unsigned long long ssel =
            (nz2 ? 0x006ull : 0ull) | (z3 ? 0x078ull : 0ull)
          | (nz5 ? 0x180ull : 0ull);
        float Ia = sel_mask(V0, V1, ssel);
        float t7a = t6 + Ia;
        float v1a = fmaf(0.25f, t7a, v);
        bool fa = (v1a >= 30.0f);
        v = fa ? c : v1a;
        float u1d = u1 + d;
        u = fa ? u1d : u1;
        psp[0] = fa ? 1.0f : 0.0f;
        pvv[0] = v;
        ++psp; ++pvv;
        z2 = nz2; z4 = nz4; z5 = nz5;
    }

    // publish detection result (ws is re-poisoned before every call)
    if (lane == 0) {
        ws[0] = (t_det >= 0) ? 1 : 0;
        ws[1] = t_det;
        ws[2] = Pf;
    }
}

// Fills out[r, t] for t in [t_det, T) with the periodic continuation
// out[r, t_det - P + ((t - t_det) mod P)]. No-op when no cycle was found.
__global__ __launch_bounds__(256) void fill_cycle(float* __restrict__ out,
                                                  const int* __restrict__ ws,
                                                  int T) {
    if (ws[0] == 0) return;
    const int t0 = ws[1];
    const int P  = ws[2];
    const int r  = blockIdx.y;                    // 0..9 (row)
    const float* __restrict__ src = out + (size_t)r * T + (t0 - P);
    float* __restrict__ dst       = out + (size_t)r * T + t0;
    const int n = T - t0;
    for (int i = blockIdx.x * blockDim.x + threadIdx.x; i < n;
         i += gridDim.x * blockDim.x) {
        dst[i] = src[i % P];
    }
}

extern "C" void kernel_launch(void* const* d_in, const int* in_sizes, int n_in,
                              void* d_out, int out_size, void* d_ws, size_t ws_size,
                              hipStream_t stream) {
    const float* mat = (const float*)d_in[0];
    const float* w   = (const float*)d_in[1];
    // out_size = 2 outputs * 5 neurons * T  -> T = out_size/10
    int T = out_size / 10;
    net_sim<<<1, 256, 0, stream>>>(mat, w, (float*)d_out, (int*)d_ws, T);
    dim3 grid(40, 10, 1);
    fill_cycle<<<grid, 256, 0, stream>>>((float*)d_out, (const int*)d_ws, T);
}